// Round 1
// baseline (1626.467 us; speedup 1.0000x reference)
//
#include <hip/hip_runtime.h>
#include <math.h>

#define N_NODES 50000
#define N_EDGES 800000
#define DIN 128
#define KU 1280   // 10*DIN
#define BM 64
#define BN 64
#define BK 16

// ---------------- utility kernels ----------------

__global__ void k_deg(const int* __restrict__ dst, int* __restrict__ deg) {
  int e = blockIdx.x * blockDim.x + threadIdx.x;
  if (e < N_EDGES) atomicAdd(&deg[dst[e]], 1);
}

// single-block exclusive scan over n ints (n ~ 50k): Hillis-Steele per 1024 chunk
__global__ void k_scan(const int* __restrict__ deg, int* __restrict__ row_off, int n) {
  __shared__ int sm[1024];
  __shared__ int carry;
  int tid = threadIdx.x;
  if (tid == 0) carry = 0;
  __syncthreads();
  for (int base = 0; base < n; base += 1024) {
    int v = (base + tid < n) ? deg[base + tid] : 0;
    sm[tid] = v;
    __syncthreads();
    for (int off = 1; off < 1024; off <<= 1) {
      int t = (tid >= off) ? sm[tid - off] : 0;
      __syncthreads();
      sm[tid] += t;
      __syncthreads();
    }
    if (base + tid < n) row_off[base + tid] = carry + sm[tid] - v;  // exclusive
    __syncthreads();
    if (tid == 1023) carry += sm[1023];
    __syncthreads();
  }
  if (tid == 0) row_off[n] = carry;
}

__global__ void k_node_init(const int* __restrict__ deg, const int* __restrict__ row_off,
                            int* __restrict__ cursor, float* __restrict__ amp,
                            float* __restrict__ att) {
  int v = blockIdx.x * blockDim.x + threadIdx.x;
  if (v >= N_NODES) return;
  cursor[v] = row_off[v];
  float d = (float)deg[v];
  float logd = logf(d + 1.0f);
  amp[v] = logd / 3.0f;
  att[v] = 3.0f / fmaxf(logd, 1e-6f);
}

__global__ void k_fill(const int* __restrict__ src, const int* __restrict__ dst,
                       int* __restrict__ cursor, int* __restrict__ nbr) {
  int e = blockIdx.x * blockDim.x + threadIdx.x;
  if (e >= N_EDGES) return;
  int v = dst[e];
  int slot = atomicAdd(&cursor[v], 1);
  nbr[slot] = src[e];
}

// ---------------- AB GEMM: AB[v][0:128]=h@Mw_top ; AB[v][128:256]=h@Mw_bot+Mb ----------------

__global__ __launch_bounds__(256) void k_gemm_ab(const float* __restrict__ X,
                                                 const float* __restrict__ Mw,
                                                 const float* __restrict__ Mb,
                                                 float* __restrict__ AB) {
  __shared__ float Xs[BK][BM + 4];
  __shared__ float Ws[BK][BN + 4];
  int tid = threadIdx.x;
  int row0 = blockIdx.x * BM;
  int col0 = blockIdx.y * BN;   // 0..255 over 4 tiles
  int tx = tid & 15, ty = tid >> 4;
  float acc[4][4] = {};
  for (int k0 = 0; k0 < DIN; k0 += BK) {
    int kk = tid & 15, rb = tid >> 4;
#pragma unroll
    for (int r = 0; r < 4; ++r) {
      int row = rb + r * 16;
      int g = row0 + row;
      Xs[kk][row] = (g < N_NODES) ? X[(long)g * DIN + k0 + kk] : 0.f;
    }
    int cc = tid & 63, kb = tid >> 6;
#pragma unroll
    for (int r = 0; r < 4; ++r) {
      int k = kb + r * 4;
      int gk = k0 + k;
      int gc = col0 + cc;
      Ws[k][cc] = (gc < DIN) ? Mw[gk * DIN + gc] : Mw[(DIN + gk) * DIN + (gc - DIN)];
    }
    __syncthreads();
#pragma unroll
    for (int k = 0; k < BK; ++k) {
      const float4 a4 = *(const float4*)&Xs[k][ty << 2];
      const float4 b4 = *(const float4*)&Ws[k][tx << 2];
      float av[4] = {a4.x, a4.y, a4.z, a4.w};
      float bv[4] = {b4.x, b4.y, b4.z, b4.w};
#pragma unroll
      for (int i = 0; i < 4; ++i)
#pragma unroll
        for (int j = 0; j < 4; ++j) acc[i][j] += av[i] * bv[j];
    }
    __syncthreads();
  }
#pragma unroll
  for (int i = 0; i < 4; ++i) {
    int g = row0 + (ty << 2) + i;
    if (g >= N_NODES) continue;
    int gc = col0 + (tx << 2);
    float4 v;
    v.x = acc[i][0]; v.y = acc[i][1]; v.z = acc[i][2]; v.w = acc[i][3];
    if (gc >= DIN) {  // whole float4 is in B half (col0 tile is 64-wide, DIN=128 aligned)
      v.x += Mb[gc - DIN]; v.y += Mb[gc + 1 - DIN]; v.z += Mb[gc + 2 - DIN]; v.w += Mb[gc + 3 - DIN];
    }
    *(float4*)&AB[(long)g * 256 + gc] = v;
  }
}

// ---------------- aggregation: one wave per node ----------------

__global__ __launch_bounds__(256) void k_agg(const float* __restrict__ AB,
                                             const int* __restrict__ row_off,
                                             const int* __restrict__ nbr,
                                             float* __restrict__ AGG) {
  int wave = blockIdx.x * 4 + (threadIdx.x >> 6);
  int lane = threadIdx.x & 63;
  if (wave >= N_NODES) return;
  int v = wave;
  int beg = row_off[v], end = row_off[v + 1];
  int c = lane * 2;
  float sx = 0.f, sy = 0.f;
  float mnx = 3.4e38f, mny = 3.4e38f;
  float mxx = -3.4e38f, mxy = -3.4e38f;
  for (int i = beg; i < end; ++i) {
    int s = nbr[i];
    const float2 a = *(const float2*)&AB[(long)s * 256 + c];
    sx += a.x; sy += a.y;
    mnx = fminf(mnx, a.x); mny = fminf(mny, a.y);
    mxx = fmaxf(mxx, a.x); mxy = fmaxf(mxy, a.y);
  }
  int d = end - beg;
  float2 b = *(const float2*)&AB[(long)v * 256 + 128 + c];
  float* o = &AGG[(long)v * 384];
  if (d > 0) {
    float inv = 1.f / (float)d;
    *(float2*)&o[c]       = make_float2(sx * inv + b.x, sy * inv + b.y);
    *(float2*)&o[128 + c] = make_float2(mnx + b.x, mny + b.y);
    *(float2*)&o[256 + c] = make_float2(mxx + b.x, mxy + b.y);
  } else {
    *(float2*)&o[c]       = make_float2(0.f, 0.f);
    *(float2*)&o[128 + c] = make_float2(0.f, 0.f);
    *(float2*)&o[256 + c] = make_float2(0.f, 0.f);
  }
}

// ---------------- U GEMM with virtual X = [h | agg | agg*amp | agg*att] ----------------

__global__ __launch_bounds__(256) void k_gemm_u(const float* __restrict__ H,
                                                const float* __restrict__ AGG,
                                                const float* __restrict__ amp,
                                                const float* __restrict__ att,
                                                const float* __restrict__ Uw,
                                                const float* __restrict__ Ub,
                                                float* __restrict__ out,
                                                int Nout, int relu) {
  __shared__ float Xs[BK][BM + 4];
  __shared__ float Ws[BK][BN + 4];
  int tid = threadIdx.x;
  int row0 = blockIdx.x * BM;
  int col0 = blockIdx.y * BN;
  int tx = tid & 15, ty = tid >> 4;
  float acc[4][4] = {};
  for (int k0 = 0; k0 < KU; k0 += BK) {
    int kk = tid & 15, rb = tid >> 4;
    // whole BK tile lies in one segment (boundaries 128/512/896 are BK-aligned)
    int seg = (k0 < DIN) ? -1 : (k0 - DIN) / 384;
    int idx0 = (k0 < DIN) ? k0 : (k0 - DIN) - seg * 384;
#pragma unroll
    for (int r = 0; r < 4; ++r) {
      int row = rb + r * 16;
      int g = row0 + row;
      float vv = 0.f;
      if (g < N_NODES) {
        if (seg < 0) {
          vv = H[(long)g * DIN + idx0 + kk];
        } else {
          vv = AGG[(long)g * 384 + idx0 + kk];
          if (seg == 1) vv *= amp[g];
          else if (seg == 2) vv *= att[g];
        }
      }
      Xs[kk][row] = vv;
    }
    int cc = tid & 63, kb = tid >> 6;
#pragma unroll
    for (int r = 0; r < 4; ++r) {
      int k = kb + r * 4;
      Ws[k][cc] = Uw[(long)(k0 + k) * Nout + col0 + cc];
    }
    __syncthreads();
#pragma unroll
    for (int k = 0; k < BK; ++k) {
      const float4 a4 = *(const float4*)&Xs[k][ty << 2];
      const float4 b4 = *(const float4*)&Ws[k][tx << 2];
      float av[4] = {a4.x, a4.y, a4.z, a4.w};
      float bv[4] = {b4.x, b4.y, b4.z, b4.w};
#pragma unroll
      for (int i = 0; i < 4; ++i)
#pragma unroll
        for (int j = 0; j < 4; ++j) acc[i][j] += av[i] * bv[j];
    }
    __syncthreads();
  }
#pragma unroll
  for (int i = 0; i < 4; ++i) {
    int g = row0 + (ty << 2) + i;
    if (g >= N_NODES) continue;
    int gc = col0 + (tx << 2);
#pragma unroll
    for (int j = 0; j < 4; ++j) {
      float v = acc[i][j] + Ub[gc + j];
      if (relu) v = fmaxf(v, 0.f);
      out[(long)g * Nout + gc + j] = v;
    }
  }
}

// ---------------- launch ----------------

extern "C" void kernel_launch(void* const* d_in, const int* in_sizes, int n_in,
                              void* d_out, int out_size, void* d_ws, size_t ws_size,
                              hipStream_t stream) {
  const float* x   = (const float*)d_in[0];
  const int*   src = (const int*)d_in[1];
  const int*   dst = (const int*)d_in[2];
  const float* Mw[3] = {(const float*)d_in[3], (const float*)d_in[7],  (const float*)d_in[11]};
  const float* Mb[3] = {(const float*)d_in[4], (const float*)d_in[8],  (const float*)d_in[12]};
  const float* Uw[3] = {(const float*)d_in[5], (const float*)d_in[9],  (const float*)d_in[13]};
  const float* Ub[3] = {(const float*)d_in[6], (const float*)d_in[10], (const float*)d_in[14]};
  float* out = (float*)d_out;

  char* ws = (char*)d_ws;
  size_t o = 0;
  auto alloc = [&](size_t bytes) -> char* {
    o = (o + 255) & ~(size_t)255;
    char* p = ws + o;
    o += bytes;
    return p;
  };
  int*   deg_i   = (int*)alloc((size_t)N_NODES * 4);
  int*   row_off = (int*)alloc((size_t)(N_NODES + 1) * 4);
  int*   cursor  = (int*)alloc((size_t)N_NODES * 4);
  float* amp     = (float*)alloc((size_t)N_NODES * 4);
  float* att     = (float*)alloc((size_t)N_NODES * 4);
  int*   nbr     = (int*)alloc((size_t)N_EDGES * 4);
  float* AB      = (float*)alloc((size_t)N_NODES * 256 * 4);
  float* AGG     = (float*)alloc((size_t)N_NODES * 384 * 4);
  float* h1      = (float*)alloc((size_t)N_NODES * 128 * 4);
  float* h2      = (float*)alloc((size_t)N_NODES * 128 * 4);

  // ---- graph structure (recomputed every call; inputs are re-poisoned) ----
  hipMemsetAsync(deg_i, 0, (size_t)N_NODES * 4, stream);
  k_deg<<<(N_EDGES + 255) / 256, 256, 0, stream>>>(dst, deg_i);
  k_scan<<<1, 1024, 0, stream>>>(deg_i, row_off, N_NODES);
  k_node_init<<<(N_NODES + 255) / 256, 256, 0, stream>>>(deg_i, row_off, cursor, amp, att);
  k_fill<<<(N_EDGES + 255) / 256, 256, 0, stream>>>(src, dst, cursor, nbr);

  const int MT = (N_NODES + BM - 1) / BM;  // 782
  const float* Hs[3]  = {x, h1, h2};
  float*       Os[3]  = {h1, h2, out};
  const int    Nouts[3] = {128, 128, 64};
  const int    relus[3] = {1, 1, 0};

  for (int L = 0; L < 3; ++L) {
    dim3 gAB(MT, 4);
    k_gemm_ab<<<gAB, 256, 0, stream>>>(Hs[L], Mw[L], Mb[L], AB);
    k_agg<<<(N_NODES + 3) / 4, 256, 0, stream>>>(AB, row_off, nbr, AGG);
    dim3 gU(MT, Nouts[L] / 64);
    k_gemm_u<<<gU, 256, 0, stream>>>(Hs[L], AGG, amp, att, Uw[L], Ub[L], Os[L], Nouts[L], relus[L]);
  }
}

// Round 2
// 948.980 us; speedup vs baseline: 1.7139x; 1.7139x over previous
//
#include <hip/hip_runtime.h>
#include <math.h>

#define N_NODES 50000
#define N_EDGES 800000
#define DIN 128
#define NB_SCAN ((N_NODES + 255) / 256)

typedef unsigned short u16;
typedef unsigned int u32;
typedef short short8 __attribute__((ext_vector_type(8)));
typedef float f32x4 __attribute__((ext_vector_type(4)));

__device__ __forceinline__ u16 f2bf(float x) {
  u32 u = __float_as_uint(x);
  u32 r = (u + 0x7FFFu + ((u >> 16) & 1u)) >> 16;
  return (u16)r;
}
__device__ __forceinline__ float bf2f(u16 h) { return __uint_as_float(((u32)h) << 16); }

__device__ __forceinline__ f32x4 mfma_bf16(short8 a, short8 b, f32x4 c) {
  return __builtin_amdgcn_mfma_f32_16x16x32_bf16(a, b, c, 0, 0, 0);
}

// swizzled byte offset within a [rows][64 bf16] tile (128B rows)
#define SWZ(row, kb) ((row) * 128 + ((kb) ^ (((row) & 7) << 4)))

// ---------------- graph setup ----------------

__global__ void k_deg(const int* __restrict__ dst, int* __restrict__ deg) {
  int e = blockIdx.x * blockDim.x + threadIdx.x;
  if (e < N_EDGES) atomicAdd(&deg[dst[e]], 1);
}

__global__ void k_scan_local(const int* __restrict__ deg, int* __restrict__ excl,
                             int* __restrict__ bsum) {
  __shared__ int sm[256];
  int tid = threadIdx.x;
  int i = blockIdx.x * 256 + tid;
  int v = (i < N_NODES) ? deg[i] : 0;
  sm[tid] = v;
  __syncthreads();
  for (int off = 1; off < 256; off <<= 1) {
    int t = (tid >= off) ? sm[tid - off] : 0;
    __syncthreads();
    sm[tid] += t;
    __syncthreads();
  }
  if (i < N_NODES) excl[i] = sm[tid] - v;
  if (tid == 255) bsum[blockIdx.x] = sm[255];
}

__global__ void k_scan_bsum(const int* __restrict__ bsum, int* __restrict__ boff,
                            int* __restrict__ row_off) {
  __shared__ int sm[256];
  int tid = threadIdx.x;
  int v = (tid < NB_SCAN) ? bsum[tid] : 0;
  sm[tid] = v;
  __syncthreads();
  for (int off = 1; off < 256; off <<= 1) {
    int t = (tid >= off) ? sm[tid - off] : 0;
    __syncthreads();
    sm[tid] += t;
    __syncthreads();
  }
  if (tid < NB_SCAN) boff[tid] = sm[tid] - v;
  if (tid == 255) row_off[N_NODES] = sm[255];
}

__global__ void k_scan_add(const int* __restrict__ excl, const int* __restrict__ boff,
                           int* __restrict__ row_off) {
  int i = blockIdx.x * 256 + threadIdx.x;
  if (i < N_NODES) row_off[i] = excl[i] + boff[i >> 8];
}

__global__ void k_node_init(const int* __restrict__ deg, const int* __restrict__ row_off,
                            int* __restrict__ cursor, float* __restrict__ amp,
                            float* __restrict__ att) {
  int v = blockIdx.x * blockDim.x + threadIdx.x;
  if (v >= N_NODES) return;
  cursor[v] = row_off[v];
  float d = (float)deg[v];
  float logd = logf(d + 1.0f);
  amp[v] = logd / 3.0f;
  att[v] = 3.0f / fmaxf(logd, 1e-6f);
}

__global__ void k_fill(const int* __restrict__ src, const int* __restrict__ dst,
                       int* __restrict__ cursor, int* __restrict__ nbr) {
  int e = blockIdx.x * blockDim.x + threadIdx.x;
  if (e >= N_EDGES) return;
  int slot = atomicAdd(&cursor[dst[e]], 1);
  nbr[slot] = src[e];
}

// ---------------- weight prep: transpose + split-bf16 ----------------

// WabT[j][k] = j<128 ? Mw[k][j] : Mw[128+k][j-128]   (j in [0,256), k in [0,128))
__global__ void k_prep_ab(const float* __restrict__ Mw, const float* __restrict__ Mb,
                          u16* __restrict__ Th, u16* __restrict__ Tl,
                          float* __restrict__ bias_ab) {
  int j = blockIdx.x;     // 0..255
  int k = threadIdx.x;    // 0..127
  float w = (j < 128) ? Mw[k * 128 + j] : Mw[(128 + k) * 128 + (j - 128)];
  u16 hi = f2bf(w);
  u16 lo = f2bf(w - bf2f(hi));
  Th[j * 128 + k] = hi;
  Tl[j * 128 + k] = lo;
  if (k == 0) bias_ab[j] = (j < 128) ? 0.f : Mb[j - 128];
}

// UwT[j][k] = Uw[k][j]   (j in [0,Nout), k in [0,1280))
__global__ void k_prep_u(const float* __restrict__ Uw, u16* __restrict__ Th,
                         u16* __restrict__ Tl, int Nout) {
  int k = blockIdx.x * 256 + threadIdx.x;  // 0..1279
  int j = blockIdx.y;
  float w = Uw[(size_t)k * Nout + j];
  u16 hi = f2bf(w);
  u16 lo = f2bf(w - bf2f(hi));
  Th[(size_t)j * 1280 + k] = hi;
  Tl[(size_t)j * 1280 + k] = lo;
}

// ---------------- unified split-bf16 MFMA GEMM ----------------
// out[M=50000][Nout] = X_virtual @ WT^T + bias, WT is [Nout][K] (hi/lo bf16)
// virt=0: X = X (stride K).  virt=1: X = [h | agg | agg*amp | agg*att] (K=1280)

template <int BN>
__global__ __launch_bounds__(256) void k_mfma_gemm(
    const float* __restrict__ X, const float* __restrict__ AGG,
    const float* __restrict__ amp, const float* __restrict__ att,
    const u16* __restrict__ WTh, const u16* __restrict__ WTl,
    const float* __restrict__ bias, float* __restrict__ out,
    int K, int Nout, int virt, int relu) {
  __shared__ __align__(16) u16 Ah[128 * 64];
  __shared__ __align__(16) u16 Al[128 * 64];
  __shared__ __align__(16) u16 Bh[BN * 64];
  __shared__ __align__(16) u16 Bl[BN * 64];

  const int tid = threadIdx.x;
  const int row0 = blockIdx.x * 128;
  const int col0 = blockIdx.y * BN;
  const int lane = tid & 63;
  const int wave = tid >> 6;
  const int wrow = (wave >> 1) * 64;
  const int wcol = (wave & 1) * (BN / 2);
  constexpr int NREP = BN / 32;

  f32x4 acc[4][NREP];
  const f32x4 zero4 = {0.f, 0.f, 0.f, 0.f};
#pragma unroll
  for (int i = 0; i < 4; ++i)
#pragma unroll
    for (int n = 0; n < NREP; ++n) acc[i][n] = zero4;

  const int sm_ = tid >> 4;          // A-stage sub-row
  const int skq = (tid & 15) * 4;    // A-stage k element offset
  const int xstride = virt ? DIN : K;

  for (int k0 = 0; k0 < K; k0 += 64) {
    __syncthreads();
    // ---- stage A (virtual X -> split bf16, swizzled) ----
    const int tk = k0 - DIN;
    const bool hseg = (!virt) || (k0 < DIN);
    const int seg = hseg ? -1 : tk / 384;
    const int idx0 = hseg ? k0 : (tk - seg * 384);
#pragma unroll
    for (int r = 0; r < 8; ++r) {
      int m = r * 16 + sm_;
      int g = row0 + m;
      float4 xv = {0.f, 0.f, 0.f, 0.f};
      if (g < N_NODES) {
        if (hseg) {
          xv = *(const float4*)(X + (long)g * xstride + idx0 + skq);
        } else {
          xv = *(const float4*)(AGG + (long)g * 384 + idx0 + skq);
          if (seg == 1) {
            float s = amp[g];
            xv.x *= s; xv.y *= s; xv.z *= s; xv.w *= s;
          } else if (seg == 2) {
            float s = att[g];
            xv.x *= s; xv.y *= s; xv.z *= s; xv.w *= s;
          }
        }
      }
      u16 h0 = f2bf(xv.x), h1 = f2bf(xv.y), h2 = f2bf(xv.z), h3 = f2bf(xv.w);
      u16 l0 = f2bf(xv.x - bf2f(h0)), l1 = f2bf(xv.y - bf2f(h1));
      u16 l2 = f2bf(xv.z - bf2f(h2)), l3 = f2bf(xv.w - bf2f(h3));
      uint2 hv, lv;
      hv.x = (u32)h0 | ((u32)h1 << 16);
      hv.y = (u32)h2 | ((u32)h3 << 16);
      lv.x = (u32)l0 | ((u32)l1 << 16);
      lv.y = (u32)l2 | ((u32)l3 << 16);
      int ad = SWZ(m, skq * 2);
      *(uint2*)((char*)Ah + ad) = hv;
      *(uint2*)((char*)Al + ad) = lv;
    }
    // ---- stage B (pre-split weights, pure copy, swizzled) ----
#pragma unroll
    for (int r = 0; r < BN / 32; ++r) {
      int op = r * 256 + tid;
      int c = op >> 3, sl = op & 7;
      const u16* srch = WTh + (size_t)(col0 + c) * K + k0 + sl * 8;
      const u16* srcl = WTl + (size_t)(col0 + c) * K + k0 + sl * 8;
      int bd = SWZ(c, sl * 16);
      *(uint4*)((char*)Bh + bd) = *(const uint4*)srch;
      *(uint4*)((char*)Bl + bd) = *(const uint4*)srcl;
    }
    __syncthreads();
    // ---- MFMA ----
#pragma unroll
    for (int kk = 0; kk < 2; ++kk) {
      const int kb = kk * 64 + (lane >> 4) * 16;
      short8 a_h[4], a_l[4];
#pragma unroll
      for (int i = 0; i < 4; ++i) {
        int rr = wrow + i * 16 + (lane & 15);
        a_h[i] = *(const short8*)((const char*)Ah + SWZ(rr, kb));
        a_l[i] = *(const short8*)((const char*)Al + SWZ(rr, kb));
      }
#pragma unroll
      for (int n = 0; n < NREP; ++n) {
        int cc = wcol + n * 16 + (lane & 15);
        short8 b_h = *(const short8*)((const char*)Bh + SWZ(cc, kb));
        short8 b_l = *(const short8*)((const char*)Bl + SWZ(cc, kb));
#pragma unroll
        for (int i = 0; i < 4; ++i) {
          acc[i][n] = mfma_bf16(a_h[i], b_h, acc[i][n]);
          acc[i][n] = mfma_bf16(a_h[i], b_l, acc[i][n]);
          acc[i][n] = mfma_bf16(a_l[i], b_h, acc[i][n]);
        }
      }
    }
  }
  // ---- epilogue ----
#pragma unroll
  for (int i = 0; i < 4; ++i) {
#pragma unroll
    for (int n = 0; n < NREP; ++n) {
      int gr0 = row0 + wrow + i * 16 + (lane >> 4) * 4;
      int gc = col0 + wcol + n * 16 + (lane & 15);
      float b = bias[gc];
#pragma unroll
      for (int q = 0; q < 4; ++q) {
        int gr = gr0 + q;
        if (gr < N_NODES) {
          float v = acc[i][n][q] + b;
          if (relu) v = fmaxf(v, 0.f);
          out[(long)gr * Nout + gc] = v;
        }
      }
    }
  }
}

// ---------------- aggregation: one wave per node (fp32) ----------------

__global__ __launch_bounds__(256) void k_agg(const float* __restrict__ AB,
                                             const int* __restrict__ row_off,
                                             const int* __restrict__ nbr,
                                             float* __restrict__ AGG) {
  int v = blockIdx.x * 4 + (threadIdx.x >> 6);
  int lane = threadIdx.x & 63;
  if (v >= N_NODES) return;
  int beg = row_off[v], end = row_off[v + 1];
  int c = lane * 2;
  float sx = 0.f, sy = 0.f;
  float mnx = 3.4e38f, mny = 3.4e38f;
  float mxx = -3.4e38f, mxy = -3.4e38f;
  for (int i = beg; i < end; ++i) {
    int s = nbr[i];
    const float2 a = *(const float2*)&AB[(long)s * 256 + c];
    sx += a.x; sy += a.y;
    mnx = fminf(mnx, a.x); mny = fminf(mny, a.y);
    mxx = fmaxf(mxx, a.x); mxy = fmaxf(mxy, a.y);
  }
  int d = end - beg;
  float2 b = *(const float2*)&AB[(long)v * 256 + 128 + c];
  float* o = &AGG[(long)v * 384];
  if (d > 0) {
    float inv = 1.f / (float)d;
    *(float2*)&o[c]       = make_float2(sx * inv + b.x, sy * inv + b.y);
    *(float2*)&o[128 + c] = make_float2(mnx + b.x, mny + b.y);
    *(float2*)&o[256 + c] = make_float2(mxx + b.x, mxy + b.y);
  } else {
    *(float2*)&o[c]       = make_float2(0.f, 0.f);
    *(float2*)&o[128 + c] = make_float2(0.f, 0.f);
    *(float2*)&o[256 + c] = make_float2(0.f, 0.f);
  }
}

// ---------------- launch ----------------

extern "C" void kernel_launch(void* const* d_in, const int* in_sizes, int n_in,
                              void* d_out, int out_size, void* d_ws, size_t ws_size,
                              hipStream_t stream) {
  const float* x   = (const float*)d_in[0];
  const int*   src = (const int*)d_in[1];
  const int*   dst = (const int*)d_in[2];
  const float* Mw[3] = {(const float*)d_in[3], (const float*)d_in[7],  (const float*)d_in[11]};
  const float* Mb[3] = {(const float*)d_in[4], (const float*)d_in[8],  (const float*)d_in[12]};
  const float* Uw[3] = {(const float*)d_in[5], (const float*)d_in[9],  (const float*)d_in[13]};
  const float* Ub[3] = {(const float*)d_in[6], (const float*)d_in[10], (const float*)d_in[14]};
  float* out = (float*)d_out;

  char* ws = (char*)d_ws;
  size_t o = 0;
  auto alloc = [&](size_t bytes) -> char* {
    o = (o + 255) & ~(size_t)255;
    char* p = ws + o;
    o += bytes;
    return p;
  };
  int*   deg_i   = (int*)alloc((size_t)N_NODES * 4);
  int*   row_off = (int*)alloc((size_t)(N_NODES + 1) * 4);
  int*   excl    = (int*)alloc((size_t)N_NODES * 4);
  int*   bsum    = (int*)alloc((size_t)NB_SCAN * 4);
  int*   boff    = (int*)alloc((size_t)NB_SCAN * 4);
  int*   cursor  = (int*)alloc((size_t)N_NODES * 4);
  float* amp     = (float*)alloc((size_t)N_NODES * 4);
  float* att     = (float*)alloc((size_t)N_NODES * 4);
  int*   nbr     = (int*)alloc((size_t)N_EDGES * 4);
  float* AB      = (float*)alloc((size_t)N_NODES * 256 * 4);
  float* AGG     = (float*)alloc((size_t)N_NODES * 384 * 4);
  float* h1      = (float*)alloc((size_t)N_NODES * 128 * 4);
  float* h2      = (float*)alloc((size_t)N_NODES * 128 * 4);
  u16*   WabTh[3]; u16* WabTl[3]; float* bias_ab[3];
  u16*   UwTh[3];  u16* UwTl[3];
  const int Nouts[3] = {128, 128, 64};
  for (int L = 0; L < 3; ++L) {
    WabTh[L] = (u16*)alloc((size_t)256 * 128 * 2);
    WabTl[L] = (u16*)alloc((size_t)256 * 128 * 2);
    bias_ab[L] = (float*)alloc(256 * 4);
    UwTh[L] = (u16*)alloc((size_t)Nouts[L] * 1280 * 2);
    UwTl[L] = (u16*)alloc((size_t)Nouts[L] * 1280 * 2);
  }

  // ---- graph structure ----
  hipMemsetAsync(deg_i, 0, (size_t)N_NODES * 4, stream);
  k_deg<<<(N_EDGES + 255) / 256, 256, 0, stream>>>(dst, deg_i);
  k_scan_local<<<NB_SCAN, 256, 0, stream>>>(deg_i, excl, bsum);
  k_scan_bsum<<<1, 256, 0, stream>>>(bsum, boff, row_off);
  k_scan_add<<<NB_SCAN, 256, 0, stream>>>(excl, boff, row_off);
  k_node_init<<<(N_NODES + 255) / 256, 256, 0, stream>>>(deg_i, row_off, cursor, amp, att);
  k_fill<<<(N_EDGES + 255) / 256, 256, 0, stream>>>(src, dst, cursor, nbr);

  // ---- weight prep ----
  for (int L = 0; L < 3; ++L) {
    k_prep_ab<<<256, 128, 0, stream>>>(Mw[L], Mb[L], WabTh[L], WabTl[L], bias_ab[L]);
    k_prep_u<<<dim3(5, Nouts[L]), 256, 0, stream>>>(Uw[L], UwTh[L], UwTl[L], Nouts[L]);
  }

  const int MT = (N_NODES + 127) / 128;  // 391
  const float* Hs[3] = {x, h1, h2};
  float*       Os[3] = {h1, h2, out};

  for (int L = 0; L < 3; ++L) {
    // AB = h @ [Mw_top | Mw_bot] (+Mb on B half)
    k_mfma_gemm<128><<<dim3(MT, 2), 256, 0, stream>>>(
        Hs[L], nullptr, amp, att, WabTh[L], WabTl[L], bias_ab[L], AB,
        DIN, 256, 0, 0);
    k_agg<<<(N_NODES + 3) / 4, 256, 0, stream>>>(AB, row_off, nbr, AGG);
    if (L < 2) {
      k_mfma_gemm<128><<<dim3(MT, 1), 256, 0, stream>>>(
          Hs[L], AGG, amp, att, UwTh[L], UwTl[L], Ub[L], Os[L],
          1280, 128, 1, 1);
    } else {
      k_mfma_gemm<64><<<dim3(MT, 1), 256, 0, stream>>>(
          Hs[L], AGG, amp, att, UwTh[L], UwTl[L], Ub[L], Os[L],
          1280, 64, 1, 0);
    }
  }
}